// Round 2
// baseline (1100.387 us; speedup 1.0000x reference)
//
#include <hip/hip_runtime.h>

// WaveRNN cell, MI355X. B=32768 H=896 S=448 Q=256.
// Inputs/outputs are FLOAT32 (per reference dtypes). Internally: convert to
// bf16, run m97-style 128x128 MFMA tiles with global_load_lds width-16
// staging, f32 epilogues.
// Pipeline: transpose weights f32->bf16T, convert prev_hidden f32->bf16,
// fused gate GEMM (3 passes over W_R columns; u,r kept packed in regs),
// stage1 relu GEMM, stage2 GEMM.

typedef unsigned short u16;
typedef unsigned int u32;
typedef __attribute__((ext_vector_type(8))) short bf16x8;
typedef __attribute__((ext_vector_type(4))) float f32x4;

#define GAS __attribute__((address_space(1)))
#define LAS __attribute__((address_space(3)))

__device__ __forceinline__ u16 f2b(float f) {
  union { float f; u32 i; } v; v.f = f;
  return (u16)((v.i + 0x7fffu + ((v.i >> 16) & 1u)) >> 16);
}

__device__ __forceinline__ void gl_lds(const u16* g, u16* l) {
  __builtin_amdgcn_global_load_lds((const GAS void*)g, (LAS void*)l, 16, 0, 0);
}

// ---------------- f32 -> bf16 convert (prev_hidden) ----------------
__global__ void cvt_f32_bf16(const float* __restrict__ in, u16* __restrict__ outp) {
  const size_t i = ((size_t)blockIdx.x * 256 + threadIdx.x) * 4;
  const float4 v = *(const float4*)&in[i];
  ushort4 o;
  o.x = f2b(v.x); o.y = f2b(v.y); o.z = f2b(v.z); o.w = f2b(v.w);
  *(ushort4*)&outp[i] = o;
}

// --------- weight transpose, f32 row-major R x C -> bf16 C x R ---------
__global__ void transpose_f32_bf16(const float* __restrict__ in, u16* __restrict__ outp,
                                   int R, int C) {
  __shared__ u16 t[32][33];
  const int c0 = blockIdx.x * 32, r0 = blockIdx.y * 32;
  const int x = threadIdx.x, y = threadIdx.y;
  #pragma unroll
  for (int i = 0; i < 32; i += 8)
    t[y + i][x] = f2b(in[(size_t)(r0 + y + i) * C + (c0 + x)]);
  __syncthreads();
  #pragma unroll
  for (int i = 0; i < 32; i += 8)
    outp[(size_t)(c0 + y + i) * R + (r0 + x)] = t[x][y + i];
}

// ------------- 128x128 tile K-loop: A row-major, BT n-major (both k-contig) --
// 4 waves as 2x2 grid of 64x64; BK=32; acc[4][4] f32x4.
__device__ __forceinline__ void gemm_tile_k(const u16* __restrict__ A, int lda,
                                            const u16* __restrict__ BT, int ldb,
                                            int K, u16* Al, u16* Bl,
                                            int wave, int lane, f32x4 (&acc)[4][4]) {
  const int wm = wave & 1, wn = wave >> 1;
  const int q = lane >> 4, l16 = lane & 15;
  const int sr = lane >> 2;          // staging sub-row 0..15
  const int sc = (lane & 3) * 8;     // staging col offset (elements)
  for (int k0 = 0; k0 < K; k0 += 32) {
    #pragma unroll
    for (int i = 0; i < 2; ++i) {
      const int rr = wave * 32 + i * 16;  // wave-uniform row base
      gl_lds(A + (size_t)(rr + sr) * lda + (k0 + sc), &Al[rr * 32]);
      gl_lds(BT + (size_t)(rr + sr) * ldb + (k0 + sc), &Bl[rr * 32]);
    }
    __syncthreads();
    bf16x8 af[4], bfr[4];
    #pragma unroll
    for (int t = 0; t < 4; ++t) {
      af[t]  = *(const bf16x8*)&Al[(wm * 64 + t * 16 + l16) * 32 + q * 8];
      bfr[t] = *(const bf16x8*)&Bl[(wn * 64 + t * 16 + l16) * 32 + q * 8];
    }
    #pragma unroll
    for (int mt = 0; mt < 4; ++mt)
      #pragma unroll
      for (int nt = 0; nt < 4; ++nt)
        acc[mt][nt] = __builtin_amdgcn_mfma_f32_16x16x32_bf16(af[mt], bfr[nt],
                                                              acc[mt][nt], 0, 0, 0);
    __syncthreads();
  }
}

__device__ __forceinline__ void zero_acc(f32x4 (&acc)[4][4]) {
  const f32x4 z = {0.f, 0.f, 0.f, 0.f};
  #pragma unroll
  for (int mt = 0; mt < 4; ++mt)
    #pragma unroll
    for (int nt = 0; nt < 4; ++nt)
      acc[mt][nt] = z;
}

// ---------------- fused gate kernel ----------------
// grid (7, 256): j0 = bx*128 in [0,896), m0 = by*128. 3 passes s=u,r,e.
// hidden written f32 to houtf (d_out) and bf16 to hb (ws).
__global__ __launch_bounds__(256, 2)
void gate_kernel(const u16* __restrict__ phb, const u16* __restrict__ wrt,
                 const float* __restrict__ phf,
                 const float* __restrict__ y2, const float* __restrict__ cc,
                 const float* __restrict__ wic, const float* __restrict__ wif,
                 const float* __restrict__ bu, const float* __restrict__ br,
                 const float* __restrict__ be,
                 float* __restrict__ houtf, u16* __restrict__ hb) {
  __shared__ u16 Al[128 * 32];
  __shared__ u16 Bl[128 * 32];
  __shared__ float rowy[3 * 128];
  const int tid = threadIdx.x;
  const int lane = tid & 63, wave = tid >> 6;
  const int m0 = blockIdx.y * 128;
  const int j0 = blockIdx.x * 128;
  if (tid < 128) {
    const int r = m0 + tid;
    rowy[tid]       = y2[2 * r];
    rowy[128 + tid] = y2[2 * r + 1];
    rowy[256 + tid] = cc[r];
  }
  const int wm = wave & 1, wn = wave >> 1;
  const int q = lane >> 4, l16 = lane & 15;

  uint2 u_pk[4][4], r_pk[4][4];

  for (int s = 0; s < 3; ++s) {
    f32x4 acc[4][4];
    zero_acc(acc);
    gemm_tile_k(phb + (size_t)m0 * 896, 896,
                wrt + (size_t)(s * 896 + j0) * 896, 896,
                896, Al, Bl, wave, lane, acc);

    const int jb = j0 + wn * 64;
    const int rb = wm * 64 + q * 4;
    if (s < 2) {
      const float* bs_arr = (s == 0) ? bu : br;
      #pragma unroll
      for (int nt = 0; nt < 4; ++nt) {
        const int j = jb + nt * 16 + l16;
        float wi0, wi1, wi2;
        if (j < 448) {
          const int jc = s * 448 + j;
          wi0 = wic[jc]; wi1 = wic[1344 + jc]; wi2 = 0.f;
        } else {
          const int jf = s * 448 + j - 448;
          wi0 = wif[jf]; wi1 = wif[1344 + jf]; wi2 = wif[2688 + jf];
        }
        const float bias = bs_arr[j];
        #pragma unroll
        for (int mt = 0; mt < 4; ++mt) {
          const int rl = rb + mt * 16;
          float t[4];
          #pragma unroll
          for (int i = 0; i < 4; ++i) {
            const float I = rowy[rl + i] * wi0 + rowy[128 + rl + i] * wi1 +
                            rowy[256 + rl + i] * wi2 + bias;
            const float g = acc[mt][nt][i] + I;
            t[i] = 1.f / (1.f + __expf(-g));
          }
          uint2 pk;
          pk.x = (u32)f2b(t[0]) | ((u32)f2b(t[1]) << 16);
          pk.y = (u32)f2b(t[2]) | ((u32)f2b(t[3]) << 16);
          if (s == 0) u_pk[mt][nt] = pk; else r_pk[mt][nt] = pk;
        }
      }
    } else {
      #pragma unroll
      for (int nt = 0; nt < 4; ++nt) {
        const int j = jb + nt * 16 + l16;
        float wi0, wi1, wi2;
        if (j < 448) {
          const int jc = 896 + j;
          wi0 = wic[jc]; wi1 = wic[1344 + jc]; wi2 = 0.f;
        } else {
          const int jf = 896 + j - 448;
          wi0 = wif[jf]; wi1 = wif[1344 + jf]; wi2 = wif[2688 + jf];
        }
        const float bias = be[j];
        #pragma unroll
        for (int mt = 0; mt < 4; ++mt) {
          const int rl = rb + mt * 16;
          const uint2 up = u_pk[mt][nt], rp = r_pk[mt][nt];
          #pragma unroll
          for (int i = 0; i < 4; ++i) {
            const float I = rowy[rl + i] * wi0 + rowy[128 + rl + i] * wi1 +
                            rowy[256 + rl + i] * wi2 + bias;
            const u32 uw = (i < 2) ? up.x : up.y;
            const u32 rw = (i < 2) ? rp.x : rp.y;
            union { u32 iu; float fu; } cu, cr;
            cu.iu = (u32)((i & 1) ? (uw & 0xffff0000u) : (uw << 16));
            cr.iu = (u32)((i & 1) ? (rw & 0xffff0000u) : (rw << 16));
            const float ev = tanhf(cr.fu * acc[mt][nt][i] + I);
            const size_t grow = (size_t)(m0 + rl + i);
            const float phv = phf[grow * 896 + j];
            const float h = cu.fu * phv + (1.f - cu.fu) * ev;
            houtf[grow * 896 + j] = h;
            hb[grow * 896 + j] = f2b(h);
          }
        }
      }
    }
  }
}

// ---------------- stage 1: T_z = relu(h_z @ W_O{1,3} + b), bf16 out ----------
// grid (4, 256, 2): n0 = bx*128 (last tile: rows >=448 of BT read garbage
// in-ws bytes; write masked by j<448; NaN confined to unwritten columns).
__global__ __launch_bounds__(256, 2)
void stage1_kernel(const u16* __restrict__ hb, const u16* __restrict__ w1t,
                   const u16* __restrict__ w3t, const float* __restrict__ b1,
                   const float* __restrict__ b3, u16* __restrict__ tc,
                   u16* __restrict__ tf) {
  __shared__ u16 Al[128 * 32];
  __shared__ u16 Bl[128 * 32];
  const int tid = threadIdx.x, lane = tid & 63, wave = tid >> 6;
  const int z = blockIdx.z;
  const int m0 = blockIdx.y * 128, n0 = blockIdx.x * 128;
  const u16* A = hb + (size_t)m0 * 896 + z * 448;
  const u16* BT = (z ? w3t : w1t) + (size_t)n0 * 448;
  const float* bias = z ? b3 : b1;
  u16* T = z ? tf : tc;
  const int wm = wave & 1, wn = wave >> 1, q = lane >> 4, l16 = lane & 15;
  f32x4 acc[4][4];
  zero_acc(acc);
  gemm_tile_k(A, 896, BT, 448, 448, Al, Bl, wave, lane, acc);
  #pragma unroll
  for (int nt = 0; nt < 4; ++nt) {
    const int j = n0 + wn * 64 + nt * 16 + l16;
    if (j < 448) {
      const float bv = bias[j];
      #pragma unroll
      for (int mt = 0; mt < 4; ++mt)
        #pragma unroll
        for (int i = 0; i < 4; ++i) {
          const size_t row = (size_t)(m0 + wm * 64 + mt * 16 + q * 4 + i);
          T[row * 448 + j] = f2b(fmaxf(acc[mt][nt][i] + bv, 0.f));
        }
    }
  }
}

// ---------------- stage 2: out_z = T_z @ W_O{2,4} + b, f32 out ----------------
// grid (2, 256, 2)
__global__ __launch_bounds__(256, 2)
void stage2_kernel(const u16* __restrict__ tc, const u16* __restrict__ tf,
                   const u16* __restrict__ w2t, const u16* __restrict__ w4t,
                   const float* __restrict__ b2_, const float* __restrict__ b4,
                   float* __restrict__ out) {
  __shared__ u16 Al[128 * 32];
  __shared__ u16 Bl[128 * 32];
  const int tid = threadIdx.x, lane = tid & 63, wave = tid >> 6;
  const int z = blockIdx.z;
  const int m0 = blockIdx.y * 128, n0 = blockIdx.x * 128;
  const u16* A = (z ? tf : tc) + (size_t)m0 * 448;
  const u16* BT = (z ? w4t : w2t) + (size_t)n0 * 448;
  const float* bias = z ? b4 : b2_;
  float* O = out + (size_t)z * 32768 * 256;
  const int wm = wave & 1, wn = wave >> 1, q = lane >> 4, l16 = lane & 15;
  f32x4 acc[4][4];
  zero_acc(acc);
  gemm_tile_k(A, 448, BT, 448, 448, Al, Bl, wave, lane, acc);
  #pragma unroll
  for (int nt = 0; nt < 4; ++nt) {
    const int j = n0 + wn * 64 + nt * 16 + l16;  // always < 256
    const float bv = bias[j];
    #pragma unroll
    for (int mt = 0; mt < 4; ++mt)
      #pragma unroll
      for (int i = 0; i < 4; ++i) {
        const size_t row = (size_t)(m0 + wm * 64 + mt * 16 + q * 4 + i);
        O[row * 256 + j] = acc[mt][nt][i] + bv;
      }
  }
}

// ---------------- host launch ----------------
extern "C" void kernel_launch(void* const* d_in, const int* in_sizes, int n_in,
                              void* d_out, int out_size, void* d_ws, size_t ws_size,
                              hipStream_t stream) {
  const float* y2   = (const float*)d_in[0];   // prev_y (B,2)
  const float* ph   = (const float*)d_in[1];   // prev_hidden (B,896)
  const float* cc   = (const float*)d_in[2];   // current_coarse (B,1)
  const float* W_R  = (const float*)d_in[3];   // (896, 2688)
  const float* W_Ic = (const float*)d_in[4];   // (2, 1344)
  const float* W_If = (const float*)d_in[5];   // (3, 1344)
  const float* W_O1 = (const float*)d_in[6];   // (448,448)
  const float* b_O1 = (const float*)d_in[7];
  const float* W_O2 = (const float*)d_in[8];   // (448,256)
  const float* b_O2 = (const float*)d_in[9];
  const float* W_O3 = (const float*)d_in[10];
  const float* b_O3 = (const float*)d_in[11];
  const float* W_O4 = (const float*)d_in[12];
  const float* b_O4 = (const float*)d_in[13];
  const float* bu   = (const float*)d_in[14];
  const float* br   = (const float*)d_in[15];
  const float* be   = (const float*)d_in[16];
  float* out = (float*)d_out;
  u16* ws  = (u16*)d_ws;

  // workspace layout (u16 elements), all offsets multiples of 8 (16B aligned)
  u16* WRT = ws;                               // 2688*896      = 2,408,448
  u16* W1T = WRT + (size_t)2688 * 896;         // 448*448
  u16* W2T = W1T + 448 * 448;                  // 256*448
  u16* W3T = W2T + 256 * 448;                  // 448*448
  u16* W4T = W3T + 448 * 448;                  // 256*448
  u16* phb = W4T + 256 * 448;                  // 32768*896 bf16
  u16* hb  = phb + (size_t)32768 * 896;        // 32768*896 bf16
  // Tc/Tf alias phb (dead after gate_kernel): 2 x 32768*448
  u16* Tc  = phb;
  u16* Tf  = phb + (size_t)32768 * 448;
  float* hidf = out + (size_t)2 * 32768 * 256; // hidden (output 2) in d_out

  dim3 tb(32, 8);
  cvt_f32_bf16<<<28672, 256, 0, stream>>>(ph, phb);
  transpose_f32_bf16<<<dim3(2688 / 32, 896 / 32), tb, 0, stream>>>(W_R, WRT, 896, 2688);
  transpose_f32_bf16<<<dim3(448 / 32, 448 / 32), tb, 0, stream>>>(W_O1, W1T, 448, 448);
  transpose_f32_bf16<<<dim3(256 / 32, 448 / 32), tb, 0, stream>>>(W_O2, W2T, 448, 256);
  transpose_f32_bf16<<<dim3(448 / 32, 448 / 32), tb, 0, stream>>>(W_O3, W3T, 448, 448);
  transpose_f32_bf16<<<dim3(256 / 32, 448 / 32), tb, 0, stream>>>(W_O4, W4T, 448, 256);

  gate_kernel<<<dim3(7, 256), 256, 0, stream>>>(phb, WRT, ph, y2, cc, W_Ic, W_If,
                                                bu, br, be, hidf, hb);
  stage1_kernel<<<dim3(4, 256, 2), 256, 0, stream>>>(hb, W1T, W3T, b_O1, b_O3,
                                                     Tc, Tf);
  stage2_kernel<<<dim3(2, 256, 2), 256, 0, stream>>>(Tc, Tf, W2T, W4T, b_O2, b_O4,
                                                     out);
}